// Round 1
// baseline (601.115 us; speedup 1.0000x reference)
//
#include <hip/hip_runtime.h>

#define N_NODES 100000
#define N_EDGES 1200000
#define DIM     64
#define SCAN_B  256
#define NB      ((N_NODES + SCAN_B - 1) / SCAN_B)      // 391 scan blocks
#define LIN_ROWS   32
#define LIN_BLOCKS (N_NODES / LIN_ROWS)                // 3125
#define CNT_BLOCKS ((N_EDGES / 4 + 255) / 256)         // 1172

typedef unsigned short ushort_t;
typedef float f4 __attribute__((ext_vector_type(4)));

__device__ inline float bf2f(ushort_t u) {
    return __uint_as_float(((unsigned int)u) << 16);
}
__device__ inline ushort_t f2bf(float f) {
    unsigned int x = __float_as_uint(f);
    unsigned int r = x + 0x7fff + ((x >> 16) & 1);   // RNE
    return (ushort_t)(r >> 16);
}

// ---------------------------------------------------------------------------
// Fused: blocks [0,LIN_BLOCKS) do xW=x@W.T+b -> bf16;
//        blocks [LIN_BLOCKS, ...) do degree counts + per-edge rank.
// GEMM v2: 32 rows/block, 8 rows/thread, float4 K-steps.
//   Inner loop: 4 ds_read_b32 (W, conflict-free) + 8 ds_read_b128 (x,
//   wave-uniform broadcast) per 32 FMAs -> half the DS ops per FLOP of v1.
// x loaded nontemporal (read exactly once).
__global__ __launch_bounds__(256) void prep_kernel(
        const float* __restrict__ x, const float* __restrict__ W,
        const float* __restrict__ b, ushort_t* __restrict__ xwb,
        const int* __restrict__ row, const int* __restrict__ col,
        int* __restrict__ cnt_r, int* __restrict__ cnt_c,
        int* __restrict__ rank) {
    __shared__ float sWt[DIM * (DIM + 1)];       // sWt[k*65+d] = W[d][k]
    __shared__ f4    sx4[LIN_ROWS][DIM / 4];     // sx4[r][kq] = x[row0+r][4kq..]

    int t = threadIdx.x;

    if (blockIdx.x >= LIN_BLOCKS) {
        // ---- count path: 4 edges/thread; rank = pre-increment row count ----
        int i = (blockIdx.x - LIN_BLOCKS) * 256 + t;
        if (i * 4 >= N_EDGES) return;
        int4 r4 = ((const int4*)row)[i];
        int4 c4 = ((const int4*)col)[i];
        int4 rk;
        rk.x = atomicAdd(&cnt_r[r4.x], 1);
        rk.y = atomicAdd(&cnt_r[r4.y], 1);
        rk.z = atomicAdd(&cnt_r[r4.z], 1);
        rk.w = atomicAdd(&cnt_r[r4.w], 1);
        ((int4*)rank)[i] = rk;
        atomicAdd(&cnt_c[c4.x], 1);
        atomicAdd(&cnt_c[c4.y], 1);
        atomicAdd(&cnt_c[c4.z], 1);
        atomicAdd(&cnt_c[c4.w], 1);
        return;
    }

    // ---- linear path ----
    int row0 = blockIdx.x * LIN_ROWS;
    for (int i = t; i < DIM * DIM; i += 256) {
        int d = i >> 6, k = i & 63;
        sWt[k * (DIM + 1) + d] = W[i];
    }
    for (int i = t; i < LIN_ROWS * (DIM / 4); i += 256) {
        int r = i >> 4, kq = i & 15;
        sx4[r][kq] = __builtin_nontemporal_load(
            (const f4*)(x + (size_t)(row0 + r) * DIM + (kq << 2)));
    }
    __syncthreads();

    int d  = t & 63;
    int rg = (t >> 6) * 8;          // 8 rows per thread

    float bd = b[d];
    float a[8];
    #pragma unroll
    for (int r = 0; r < 8; r++) a[r] = bd;

    #pragma unroll
    for (int kq = 0; kq < DIM / 4; kq++) {
        float w0 = sWt[(4 * kq + 0) * (DIM + 1) + d];
        float w1 = sWt[(4 * kq + 1) * (DIM + 1) + d];
        float w2 = sWt[(4 * kq + 2) * (DIM + 1) + d];
        float w3 = sWt[(4 * kq + 3) * (DIM + 1) + d];
        #pragma unroll
        for (int r = 0; r < 8; r++) {
            f4 v = sx4[rg + r][kq];  // wave-uniform -> LDS broadcast
            a[r] = fmaf(v.w, w3, fmaf(v.z, w2, fmaf(v.y, w1, fmaf(v.x, w0, a[r]))));
        }
    }
    #pragma unroll
    for (int r = 0; r < 8; r++)
        xwb[(size_t)(row0 + rg + r) * DIM + d] = f2bf(a[r]);
}

// ---------------------------------------------------------------------------
// scan phase A (+ fused dinv computation)
__global__ void scan_a(const int* __restrict__ cnt_r, const int* __restrict__ cnt_c,
                       int* __restrict__ offsets, int* __restrict__ partials,
                       float* __restrict__ dinv_i, float* __restrict__ dinv_j) {
    __shared__ int s[SCAN_B];
    int t = threadIdx.x;
    int i = blockIdx.x * SCAN_B + t;
    int v = (i < N_NODES) ? cnt_r[i] : 0;
    if (i < N_NODES) {
        dinv_i[i] = rsqrtf(1.0f + (float)v);
        dinv_j[i] = rsqrtf(1.0f + (float)cnt_c[i]);
    }
    s[t] = v;
    __syncthreads();
    for (int off = 1; off < SCAN_B; off <<= 1) {
        int add = (t >= off) ? s[t - off] : 0;
        __syncthreads();
        s[t] += add;
        __syncthreads();
    }
    if (i < N_NODES) offsets[i] = s[t] - v;           // exclusive within block
    if (t == SCAN_B - 1) partials[blockIdx.x] = s[t]; // block total
}

// scan phase C with fused cross-block reduction
__global__ void scan_c(int* __restrict__ offsets, const int* __restrict__ partials) {
    __shared__ int sred[SCAN_B];
    int t = threadIdx.x, bid = blockIdx.x;
    int v = 0;
    for (int j = t; j < NB; j += SCAN_B)
        if (j < bid) v += partials[j];
    sred[t] = v;
    __syncthreads();
    for (int off = SCAN_B / 2; off > 0; off >>= 1) {
        if (t < off) sred[t] += sred[t + off];
        __syncthreads();
    }
    int base = sred[0];
    int i = bid * SCAN_B + t;
    if (i < N_NODES) offsets[i] += base;
}

// ---------------------------------------------------------------------------
// bin v3: NO atomics — pos = offsets[row] + rank. 4 edges/thread.
__global__ void bin_kernel(const int* __restrict__ row, const int* __restrict__ col,
                           const int* __restrict__ rank, const int* __restrict__ offsets,
                           int2* __restrict__ rec) {
    int i = blockIdx.x * blockDim.x + threadIdx.x;
    if (i * 4 >= N_EDGES) return;
    int4 r4 = ((const int4*)row)[i];
    int4 c4 = ((const int4*)col)[i];
    int4 k4 = ((const int4*)rank)[i];
    int e = i * 4;
    rec[offsets[r4.x] + k4.x] = make_int2(e + 0, c4.x);
    rec[offsets[r4.y] + k4.y] = make_int2(e + 1, c4.y);
    rec[offsets[r4.z] + k4.z] = make_int2(e + 2, c4.z);
    rec[offsets[r4.w] + k4.w] = make_int2(e + 3, c4.w);
}

// ---------------------------------------------------------------------------
// Gather v5: wave/node, 4 groups x 16 lanes, float4/lane.
//   - edge_attr loads NONTEMPORAL: the 307 MB once-read stream no longer
//     thrashes the 256 MiB LLC, so the random xwb/rec/dinv_j gathers stay
//     LLC-resident (predict: FETCH_SIZE drop, latency drop).
//   - depth-2 payload pipeline (ea/xw/vj two iterations ahead), depth-3 rec.
//   - out stored nontemporal (never re-read).
__global__ __launch_bounds__(256) void gather_kernel(
        const int* __restrict__ offsets, const int* __restrict__ cnt_r,
        const int2* __restrict__ rec,
        const float* __restrict__ edge_attr, const ushort_t* __restrict__ xwb,
        const float* __restrict__ dinv_i, const float* __restrict__ dinv_j,
        const float* __restrict__ root, float* __restrict__ out) {
    int lane = threadIdx.x & 63;
    int g    = lane >> 4;
    int q    = (lane & 15) << 2;
    int n    = blockIdx.x * 4 + (threadIdx.x >> 6);

    int   start = offsets[n];
    int   cnt   = cnt_r[n];
    float di    = dinv_i[n];

    // epilogue data, issued early (L2/LLC resident)
    const ushort4 xun0 = *(const ushort4*)(xwb + (size_t)n * DIM + q);
    const f4      rt   = *(const f4*)(root + q);
    const float   vj0  = dinv_j[n];

    f4 acc = {0.f, 0.f, 0.f, 0.f};
    int k = g;
    if (k < cnt) {
        int2 rc0 = rec[start + k];          // in-bounds
        int2 rc1 = rec[start + k + 4];      // over-reads land in ws slack
        int2 rc2 = rec[start + k + 8];
        f4 ea0 = __builtin_nontemporal_load(
            (const f4*)(edge_attr + (size_t)rc0.x * DIM + q));
        ushort4 xu0 = *(const ushort4*)(xwb + (size_t)rc0.y * DIM + q);
        float   vjA = dinv_j[rc0.y];
        bool m1 = (k + 4) < cnt;
        f4 ea1; ushort4 xu1; float vjB;
        if (m1) {                            // rc1 valid iff m1
            ea1 = __builtin_nontemporal_load(
                (const f4*)(edge_attr + (size_t)rc1.x * DIM + q));
            xu1 = *(const ushort4*)(xwb + (size_t)rc1.y * DIM + q);
            vjB = dinv_j[rc1.y];
        }
        for (;;) {
            bool m2 = (k + 8) < cnt;
            int2 rc3 = rec[start + k + 12];  // rec 3 ahead, unconditional
            f4 ea2; ushort4 xu2; float vjC;
            if (m2) {                        // rc2 valid iff m2
                ea2 = __builtin_nontemporal_load(
                    (const f4*)(edge_attr + (size_t)rc2.x * DIM + q));
                xu2 = *(const ushort4*)(xwb + (size_t)rc2.y * DIM + q);
                vjC = dinv_j[rc2.y];
            }
            float vv = di * vjA;
            acc.x = fmaf(vv, ea0.x + bf2f(xu0.x), acc.x);
            acc.y = fmaf(vv, ea0.y + bf2f(xu0.y), acc.y);
            acc.z = fmaf(vv, ea0.z + bf2f(xu0.z), acc.z);
            acc.w = fmaf(vv, ea0.w + bf2f(xu0.w), acc.w);
            if (!m1) break;
            k += 4;
            ea0 = ea1; xu0 = xu1; vjA = vjB;
            ea1 = ea2; xu1 = xu2; vjB = vjC;
            m1 = m2; rc2 = rc3;
        }
    }

    acc.x += __shfl_xor(acc.x, 16); acc.y += __shfl_xor(acc.y, 16);
    acc.z += __shfl_xor(acc.z, 16); acc.w += __shfl_xor(acc.w, 16);
    acc.x += __shfl_xor(acc.x, 32); acc.y += __shfl_xor(acc.y, 32);
    acc.z += __shfl_xor(acc.z, 32); acc.w += __shfl_xor(acc.w, 32);

    if (g == 0) {
        float s = di * vj0;
        f4 o;
        o.x = fmaxf(acc.x, 0.f) + fmaxf(bf2f(xun0.x) + rt.x, 0.f) * s;
        o.y = fmaxf(acc.y, 0.f) + fmaxf(bf2f(xun0.y) + rt.y, 0.f) * s;
        o.z = fmaxf(acc.z, 0.f) + fmaxf(bf2f(xun0.z) + rt.z, 0.f) * s;
        o.w = fmaxf(acc.w, 0.f) + fmaxf(bf2f(xun0.w) + rt.w, 0.f) * s;
        __builtin_nontemporal_store(o, (f4*)(out + (size_t)n * DIM + q));
    }
}

// ---------------------------------------------------------------------------
extern "C" void kernel_launch(void* const* d_in, const int* in_sizes, int n_in,
                              void* d_out, int out_size, void* d_ws, size_t ws_size,
                              hipStream_t stream) {
    const float* x         = (const float*)d_in[0];
    const int*   edge_idx  = (const int*)d_in[1];
    const float* edge_attr = (const float*)d_in[2];
    const float* W         = (const float*)d_in[3];
    const float* b         = (const float*)d_in[4];
    const float* root_emb  = (const float*)d_in[5];
    float*       out       = (float*)d_out;

    const int* row = edge_idx;
    const int* col = edge_idx + N_EDGES;

    // ws: xwb[N*D] bf16 | cnt_r,cnt_c,dinv_i,dinv_j,offsets [N] | partials[1024]
    //     | rank[E] | rec[E] int2 (LAST: gather over-reads rec by <=96 B into
    //     the remaining ~1.17 GB of ws slack)                     (~29.6 MB)
    char* ws = (char*)d_ws;
    ushort_t* xwb      = (ushort_t*)ws;   ws += (size_t)N_NODES * DIM * 2;
    int*      cnt_r    = (int*)ws;        ws += (size_t)N_NODES * 4;
    int*      cnt_c    = (int*)ws;        ws += (size_t)N_NODES * 4;
    float*    dinv_i   = (float*)ws;      ws += (size_t)N_NODES * 4;
    float*    dinv_j   = (float*)ws;      ws += (size_t)N_NODES * 4;
    int*      offsets  = (int*)ws;        ws += (size_t)N_NODES * 4;
    int*      partials = (int*)ws;        ws += 1024 * 4;
    int*      rank     = (int*)ws;        ws += (size_t)N_EDGES * 4;
    int2*     rec      = (int2*)ws;       ws += (size_t)N_EDGES * 8;

    hipMemsetAsync(cnt_r, 0, (size_t)N_NODES * 2 * sizeof(int), stream);

    prep_kernel<<<LIN_BLOCKS + CNT_BLOCKS, 256, 0, stream>>>(
        x, W, b, xwb, row, col, cnt_r, cnt_c, rank);

    scan_a<<<NB, SCAN_B, 0, stream>>>(cnt_r, cnt_c, offsets, partials, dinv_i, dinv_j);
    scan_c<<<NB, SCAN_B, 0, stream>>>(offsets, partials);

    bin_kernel<<<CNT_BLOCKS, 256, 0, stream>>>(row, col, rank, offsets, rec);

    gather_kernel<<<N_NODES / 4, 256, 0, stream>>>(
        offsets, cnt_r, rec, edge_attr, xwb, dinv_i, dinv_j, root_emb, out);
}